// Round 9
// baseline (75.745 us; speedup 1.0000x reference)
//
#include <hip/hip_runtime.h>
#include <hip/hip_bf16.h>

// HeteroLinear: out[b,n,o] = sum_i x[b,n,i] * W[t[n]][o][i] + bias[t[n]][o]
// B=16, N=16384, F_IN=F_OUT=128, NUM_TYPES=16, fp32 in/out.
//
// Round 9: SPLIT-TILE. R4/R8 plateau at ~59us real: in-flight-bytes bound,
// waves/CU capped at 16 by per-wave regs (64 VGPR + 32 AGPR acc = 96).
// Now each node is computed by a WAVE PAIR: each wave owns a 16x64 output
// half (acc 16 regs, frags 32, xv transient 32 -> combined ~70), raising
// occupancy to ~24 waves/CU (+50% TLP). Both waves of a pair load the same
// x (L1/L2-absorbed; x is L3-resident on replays). NPB=4 nodes/block,
// grid 4112. Prep = R8's proven hist+scatter with NPB=4. Math unchanged.

#define NN 16384
#define FF 128
#define NT 16
#define NPB 4            // nodes per main block (4 wave-pairs x 1 node)
#define NBLK (NN / NPB + NT)          // 4112 (upper bound on real blocks)
#define PB 64            // prep blocks
#define WS_PORD 64
#define WS_BH (WS_PORD + NBLK * NPB)  // per-(type,block) hist region

typedef __bf16 bf16x8 __attribute__((ext_vector_type(8)));
typedef float  f32x4  __attribute__((ext_vector_type(4)));

// ws int layout: [48] = #real blocks; [WS_PORD : WS_PORD+NBLK*NPB) packed
// node table (t<<20 | invalid<<16 | n); [WS_BH : WS_BH+NT*PB) hist.

__global__ __launch_bounds__(256) void hl_hist(const int* __restrict__ tv,
                                               int* __restrict__ ws) {
    __shared__ int wh[4][NT];
    const int tid = threadIdx.x, lane = tid & 63, wv = tid >> 6;
    const int t = tv[blockIdx.x * 256 + tid];
#pragma unroll
    for (int ty = 0; ty < NT; ++ty) {
        const unsigned long long m = __ballot(t == ty);
        if (lane == 0) wh[wv][ty] = __popcll(m);
    }
    __syncthreads();
    if (tid < NT)
        ws[WS_BH + tid * PB + blockIdx.x] = wh[0][tid] + wh[1][tid] + wh[2][tid] + wh[3][tid];
}

__global__ __launch_bounds__(256) void hl_scatter(const int* __restrict__ tv,
                                                  int* __restrict__ ws) {
    __shared__ int bh[NT * PB];
    __shared__ int scnt[NT], mybase[NT], sblk[NT + 1];
    __shared__ int wh[4][NT], wbase[4][NT];
    const int tid = threadIdx.x, lane = tid & 63, wv = tid >> 6;

    for (int i = tid; i < NT * PB; i += 256) bh[i] = ws[WS_BH + i];

    const int n = blockIdx.x * 256 + tid;
    const int t = tv[n];
    int myrank = 0;
#pragma unroll
    for (int ty = 0; ty < NT; ++ty) {
        const unsigned long long m = __ballot(t == ty);
        if (lane == 0) wh[wv][ty] = __popcll(m);
        if (t == ty) myrank = __popcll(m & ((1ull << lane) - 1ull));
    }
    __syncthreads();
    if (tid < NT) {                 // per-type: global count + my block's base
        int acc = 0, myb = 0;
        for (int b = 0; b < PB; ++b) {
            if (b == (int)blockIdx.x) myb = acc;
            acc += bh[tid * PB + b];
        }
        scnt[tid] = acc;
        mybase[tid] = myb;
    }
    __syncthreads();
    if (tid == 0) {                 // padded block offsets per type
        int bacc = 0;
        for (int ty = 0; ty < NT; ++ty) {
            sblk[ty] = bacc;
            bacc += (scnt[ty] + NPB - 1) / NPB;
        }
        sblk[NT] = bacc;
        if (blockIdx.x == 0) ws[48] = bacc;
    }
    __syncthreads();
    if (tid < NT) {
        int base = sblk[tid] * NPB + mybase[tid];
        for (int w = 0; w < 4; ++w) { wbase[w][tid] = base; base += wh[w][tid]; }
    }
    __syncthreads();
    ws[WS_PORD + wbase[wv][t] + myrank] = (t << 20) | n;     // valid entry

    if (blockIdx.x == 0 && tid < NT) {                       // typed sentinels
        const int lo = sblk[tid] * NPB + scnt[tid];
        const int hi = sblk[tid + 1] * NPB;
        for (int s = lo; s < hi; ++s) ws[WS_PORD + s] = (tid << 20) | 0x10000;
    }
}

__global__ __launch_bounds__(512, 4) void hl_main(
    const float* __restrict__ x,      // [16][NN][128]
    const float* __restrict__ W,      // [16][128][128]
    const float* __restrict__ bias,   // [16][128]
    const int*   __restrict__ ws,
    float*       __restrict__ out)    // [16][NN][128]
{
    const int lane = threadIdx.x & 63;
    const int wvid = threadIdx.x >> 6;   // 0..7
    const int p    = wvid >> 1;          // wave-pair 0..3 -> node slot
    const int h    = wvid & 1;           // o-half: 0 -> o<64, 1 -> o>=64
    const int bid  = blockIdx.x;

    // one independent load per node slot — no dependent chain
    const int e = ws[WS_PORD + bid * NPB + p];
    if (bid >= ws[48]) return;

    const int  t = e >> 20;
    const bool v = !(e & 0x10000);
    const int  n = e & 0x3FFF;

    const int lrow = lane & 15;   // A row (b) / B col (o) / D col (o)
    const int lgrp = lane >> 4;   // k-group of 8 / D row-group

    // x loads in flight under W staging (both waves of pair load same x)
    const float* xbase = x + (size_t)lrow * ((size_t)NN * FF) + lgrp * 8;
    f32x4 xv[8];
#pragma unroll
    for (int kk = 0; kk < 4; ++kk) {
        const float* xp = xbase + (size_t)n * FF + kk * 32;
        xv[2 * kk]     = *(const f32x4*)xp;
        xv[2 * kk + 1] = *(const f32x4*)(xp + 4);
    }

    float bv[4];
#pragma unroll
    for (int ot = 0; ot < 4; ++ot) bv[ot] = bias[t * FF + (h * 4 + ot) * 16 + lrow];

    // stage W[t] as bf16 [o][k], 256B/row, XOR-swizzled 16B slots
    __shared__ __align__(16) unsigned char Wl[FF * 256];
    const float* Wt = W + t * (FF * FF);
#pragma unroll
    for (int ii = 0; ii < 4; ++ii) {
        const int idx = ii * 512 + threadIdx.x;
        const float* ptr = Wt + idx * 8;
        f32x4 a = *(const f32x4*)ptr;
        f32x4 b = *(const f32x4*)(ptr + 4);
        bf16x8 vv;
#pragma unroll
        for (int j = 0; j < 4; ++j) { vv[j] = (__bf16)a[j]; vv[4 + j] = (__bf16)b[j]; }
        const int o  = idx >> 4;
        const int cb = (idx & 15) << 4;
        *(bf16x8*)(Wl + o * 256 + (cb ^ ((o & 7) << 4))) = vv;
    }
    __syncthreads();

    // convert x to hi/lo bf16 (consumes xv)
    bf16x8 ahi[4], alo[4];
#pragma unroll
    for (int kk = 0; kk < 4; ++kk) {
#pragma unroll
        for (int j = 0; j < 4; ++j) {
            const float f0 = xv[2 * kk][j], f1 = xv[2 * kk + 1][j];
            const __bf16 h0 = (__bf16)f0, h1 = (__bf16)f1;
            ahi[kk][j]     = h0;  alo[kk][j]     = (__bf16)(f0 - (float)h0);
            ahi[kk][4 + j] = h1;  alo[kk][4 + j] = (__bf16)(f1 - (float)h1);
        }
    }

    // MFMA over this wave's o-half (4 o-tiles)
    f32x4 acc[4];
#pragma unroll
    for (int ot = 0; ot < 4; ++ot) acc[ot] = (f32x4){0.f, 0.f, 0.f, 0.f};
#pragma unroll
    for (int kk = 0; kk < 4; ++kk) {
#pragma unroll
        for (int ot = 0; ot < 4; ++ot) {
            const int o  = (h * 4 + ot) * 16 + lrow;
            const int cb = (kk * 64 + lgrp * 16) ^ ((o & 7) << 4);
            const bf16x8 wf = *(const bf16x8*)(Wl + o * 256 + cb);
            acc[ot] = __builtin_amdgcn_mfma_f32_16x16x32_bf16(ahi[kk], wf, acc[ot], 0, 0, 0);
            acc[ot] = __builtin_amdgcn_mfma_f32_16x16x32_bf16(alo[kk], wf, acc[ot], 0, 0, 0);
        }
    }

    if (v) {
#pragma unroll
        for (int ot = 0; ot < 4; ++ot) {
            const int o = (h * 4 + ot) * 16 + lrow;
#pragma unroll
            for (int r = 0; r < 4; ++r) {
                out[(size_t)(lgrp * 4 + r) * ((size_t)NN * FF) + (size_t)n * FF + o]
                    = acc[ot][r] + bv[ot];
            }
        }
    }
}

extern "C" void kernel_launch(void* const* d_in, const int* in_sizes, int n_in,
                              void* d_out, int out_size, void* d_ws, size_t ws_size,
                              hipStream_t stream) {
    const float* x    = (const float*)d_in[0];
    const int*   tv   = (const int*)d_in[1];
    const float* W    = (const float*)d_in[2];
    const float* bias = (const float*)d_in[3];
    float*       out  = (float*)d_out;
    int*         wsI  = (int*)d_ws;

    hl_hist<<<PB, 256, 0, stream>>>(tv, wsI);
    hl_scatter<<<PB, 256, 0, stream>>>(tv, wsI);
    hl_main<<<NBLK, 512, 0, stream>>>(x, W, bias, wsI, out);
}

// Round 10
// 73.437 us; speedup vs baseline: 1.0314x; 1.0314x over previous
//
#include <hip/hip_runtime.h>
#include <hip/hip_bf16.h>

// HeteroLinear: out[b,n,o] = sum_i x[b,n,i] * W[t[n]][o][i] + bias[t[n]][o]
// B=16, N=16384, F_IN=F_OUT=128, NUM_TYPES=16, fp32 in/out.
//
// Round 10: PERSISTENT CHUNKS. R4/R8/R9 all pinned at ~90us profiled
// regardless of occupancy (R9: occ 57%, worse) -> per-block startup chain
// (~1000cy) x ~1000-4000 blocks + 1-deep pipelines was the cost, not TLP.
// Now: 528 blocks (2/CU, all resident at t=0), 8 waves x 4 nodes serial,
// W staged once per 32 nodes, 4-node unrolled loop ping-pongs two NAMED
// x buffers (R8's spill-free pattern) so next-x is always in flight under
// current node's MFMA+stores. porder read = one dwordx4 per wave. MFMA in
// two o-halves (acc[4]) to keep unified VGPR+AGPR ~100 < 128 cap.

#define NN 16384
#define FF 128
#define NT 16
#define NPB 32           // nodes per block (8 waves x 4 nodes)
#define NBLK (NN / NPB + NT)          // 528 (upper bound on real blocks)
#define PB 64            // prep blocks
#define WS_PORD 64
#define WS_BH (WS_PORD + NBLK * NPB)  // per-(type,block) hist region

typedef __bf16 bf16x8 __attribute__((ext_vector_type(8)));
typedef float  f32x4  __attribute__((ext_vector_type(4)));

// ws int layout: [48] = #real blocks; [WS_PORD : WS_PORD+NBLK*NPB) packed
// node table (t<<20 | invalid<<16 | n); [WS_BH : WS_BH+NT*PB) hist.

__global__ __launch_bounds__(256) void hl_hist(const int* __restrict__ tv,
                                               int* __restrict__ ws) {
    __shared__ int wh[4][NT];
    const int tid = threadIdx.x, lane = tid & 63, wv = tid >> 6;
    const int t = tv[blockIdx.x * 256 + tid];
#pragma unroll
    for (int ty = 0; ty < NT; ++ty) {
        const unsigned long long m = __ballot(t == ty);
        if (lane == 0) wh[wv][ty] = __popcll(m);
    }
    __syncthreads();
    if (tid < NT)
        ws[WS_BH + tid * PB + blockIdx.x] = wh[0][tid] + wh[1][tid] + wh[2][tid] + wh[3][tid];
}

__global__ __launch_bounds__(256) void hl_scatter(const int* __restrict__ tv,
                                                  int* __restrict__ ws) {
    __shared__ int bh[NT * PB];
    __shared__ int scnt[NT], mybase[NT], sblk[NT + 1];
    __shared__ int wh[4][NT], wbase[4][NT];
    const int tid = threadIdx.x, lane = tid & 63, wv = tid >> 6;

    for (int i = tid; i < NT * PB; i += 256) bh[i] = ws[WS_BH + i];

    const int n = blockIdx.x * 256 + tid;
    const int t = tv[n];
    int myrank = 0;
#pragma unroll
    for (int ty = 0; ty < NT; ++ty) {
        const unsigned long long m = __ballot(t == ty);
        if (lane == 0) wh[wv][ty] = __popcll(m);
        if (t == ty) myrank = __popcll(m & ((1ull << lane) - 1ull));
    }
    __syncthreads();
    if (tid < NT) {                 // per-type: global count + my block's base
        int acc = 0, myb = 0;
        for (int b = 0; b < PB; ++b) {
            if (b == (int)blockIdx.x) myb = acc;
            acc += bh[tid * PB + b];
        }
        scnt[tid] = acc;
        mybase[tid] = myb;
    }
    __syncthreads();
    if (tid == 0) {                 // padded block offsets per type
        int bacc = 0;
        for (int ty = 0; ty < NT; ++ty) {
            sblk[ty] = bacc;
            bacc += (scnt[ty] + NPB - 1) / NPB;
        }
        sblk[NT] = bacc;
        if (blockIdx.x == 0) ws[48] = bacc;
    }
    __syncthreads();
    if (tid < NT) {
        int base = sblk[tid] * NPB + mybase[tid];
        for (int w = 0; w < 4; ++w) { wbase[w][tid] = base; base += wh[w][tid]; }
    }
    __syncthreads();
    ws[WS_PORD + wbase[wv][t] + myrank] = (t << 20) | n;     // valid entry

    if (blockIdx.x == 0 && tid < NT) {                       // typed sentinels
        const int lo = sblk[tid] * NPB + scnt[tid];
        const int hi = sblk[tid + 1] * NPB;
        for (int s = lo; s < hi; ++s) ws[WS_PORD + s] = (tid << 20) | 0x10000;
    }
}

// ---- fully inlined building blocks (textual macros: no helper-fn SROA trap)
#define LOAD_X(XV, N)                                                        \
    _Pragma("unroll")                                                        \
    for (int kk = 0; kk < 4; ++kk) {                                         \
        const float* xp = xbase + (size_t)(N) * FF + kk * 32;                \
        XV[2 * kk]     = *(const f32x4*)xp;                                  \
        XV[2 * kk + 1] = *(const f32x4*)(xp + 4);                            \
    }

#define CVT_SPLIT(XV)                                                        \
    _Pragma("unroll")                                                        \
    for (int kk = 0; kk < 4; ++kk) {                                         \
        _Pragma("unroll")                                                    \
        for (int j = 0; j < 4; ++j) {                                        \
            const float f0 = XV[2 * kk][j], f1 = XV[2 * kk + 1][j];          \
            const __bf16 h0 = (__bf16)f0, h1 = (__bf16)f1;                   \
            ahi[kk][j]     = h0;  alo[kk][j]     = (__bf16)(f0 - (float)h0); \
            ahi[kk][4 + j] = h1;  alo[kk][4 + j] = (__bf16)(f1 - (float)h1); \
        }                                                                    \
    }

#define COMPUTE_HALF(N, V, H)                                                \
    {                                                                        \
        f32x4 acc[4];                                                        \
        _Pragma("unroll")                                                    \
        for (int ot = 0; ot < 4; ++ot) acc[ot] = (f32x4){0.f, 0.f, 0.f, 0.f};\
        _Pragma("unroll")                                                    \
        for (int kk = 0; kk < 4; ++kk) {                                     \
            _Pragma("unroll")                                                \
            for (int ot = 0; ot < 4; ++ot) {                                 \
                const int o  = ((H) * 4 + ot) * 16 + lrow;                   \
                const int cb = (kk * 64 + lgrp * 16) ^ ((o & 7) << 4);       \
                const bf16x8 wf = *(const bf16x8*)(Wl + o * 256 + cb);       \
                acc[ot] = __builtin_amdgcn_mfma_f32_16x16x32_bf16(ahi[kk], wf, acc[ot], 0, 0, 0); \
                acc[ot] = __builtin_amdgcn_mfma_f32_16x16x32_bf16(alo[kk], wf, acc[ot], 0, 0, 0); \
            }                                                                \
        }                                                                    \
        if (V) {                                                             \
            _Pragma("unroll")                                                \
            for (int ot = 0; ot < 4; ++ot) {                                 \
                const int o = ((H) * 4 + ot) * 16 + lrow;                    \
                _Pragma("unroll")                                            \
                for (int r = 0; r < 4; ++r)                                  \
                    out[(size_t)(lgrp * 4 + r) * ((size_t)NN * FF)           \
                        + (size_t)(N) * FF + o] = acc[ot][r] + bv[(H) * 4 + ot]; \
            }                                                                \
        }                                                                    \
    }

__global__ __launch_bounds__(512, 4) void hl_main(
    const float* __restrict__ x,      // [16][NN][128]
    const float* __restrict__ W,      // [16][128][128]
    const float* __restrict__ bias,   // [16][128]
    const int*   __restrict__ ws,
    float*       __restrict__ out)    // [16][NN][128]
{
    const int lane = threadIdx.x & 63;
    const int wv   = threadIdx.x >> 6;   // 0..7
    const int bid  = blockIdx.x;

    // this wave's 4 nodes: ONE 16B load
    const int4 e4 = *(const int4*)&ws[WS_PORD + bid * NPB + wv * 4];
    if (bid >= ws[48]) return;

    const int  t  = e4.x >> 20;
    const int  n0 = e4.x & 0x3FFF, n1 = e4.y & 0x3FFF;
    const int  n2 = e4.z & 0x3FFF, n3 = e4.w & 0x3FFF;
    const bool v0 = !(e4.x & 0x10000), v1 = !(e4.y & 0x10000);
    const bool v2 = !(e4.z & 0x10000), v3 = !(e4.w & 0x10000);

    const int lrow = lane & 15;   // A row (b) / B col (o) / D col (o)
    const int lgrp = lane >> 4;   // k-group of 8 / D row-group

    const float* xbase = x + (size_t)lrow * ((size_t)NN * FF) + lgrp * 8;

    f32x4  xvA[8], xvB[8];
    bf16x8 ahi[4], alo[4];

    // node-0 x loads in flight under W staging
    LOAD_X(xvA, n0);

    float bv[8];
#pragma unroll
    for (int ot = 0; ot < 8; ++ot) bv[ot] = bias[t * FF + ot * 16 + lrow];

    // stage W[t] as bf16 [o][k], 256B/row, XOR-swizzled 16B slots
    __shared__ __align__(16) unsigned char Wl[FF * 256];
    const float* Wt = W + t * (FF * FF);
#pragma unroll
    for (int ii = 0; ii < 4; ++ii) {
        const int idx = ii * 512 + threadIdx.x;
        const float* p = Wt + idx * 8;
        f32x4 a = *(const f32x4*)p;
        f32x4 b = *(const f32x4*)(p + 4);
        bf16x8 vv;
#pragma unroll
        for (int j = 0; j < 4; ++j) { vv[j] = (__bf16)a[j]; vv[4 + j] = (__bf16)b[j]; }
        const int o  = idx >> 4;
        const int cb = (idx & 15) << 4;
        *(bf16x8*)(Wl + o * 256 + (cb ^ ((o & 7) << 4))) = vv;
    }
    __syncthreads();

    // ---- node 0 (prefetch node 1) ----
    CVT_SPLIT(xvA);
    LOAD_X(xvB, n1);
    __builtin_amdgcn_sched_barrier(0);
    COMPUTE_HALF(n0, v0, 0);
    COMPUTE_HALF(n0, v0, 1);

    // ---- node 1 (prefetch node 2) ----
    CVT_SPLIT(xvB);
    LOAD_X(xvA, n2);
    __builtin_amdgcn_sched_barrier(0);
    COMPUTE_HALF(n1, v1, 0);
    COMPUTE_HALF(n1, v1, 1);

    // ---- node 2 (prefetch node 3) ----
    CVT_SPLIT(xvA);
    LOAD_X(xvB, n3);
    __builtin_amdgcn_sched_barrier(0);
    COMPUTE_HALF(n2, v2, 0);
    COMPUTE_HALF(n2, v2, 1);

    // ---- node 3 ----
    CVT_SPLIT(xvB);
    COMPUTE_HALF(n3, v3, 0);
    COMPUTE_HALF(n3, v3, 1);
}

extern "C" void kernel_launch(void* const* d_in, const int* in_sizes, int n_in,
                              void* d_out, int out_size, void* d_ws, size_t ws_size,
                              hipStream_t stream) {
    const float* x    = (const float*)d_in[0];
    const int*   tv   = (const int*)d_in[1];
    const float* W    = (const float*)d_in[2];
    const float* bias = (const float*)d_in[3];
    float*       out  = (float*)d_out;
    int*         wsI  = (int*)d_ws;

    hl_hist<<<PB, 256, 0, stream>>>(tv, wsI);
    hl_scatter<<<PB, 256, 0, stream>>>(tv, wsI);
    hl_main<<<NBLK, 512, 0, stream>>>(x, W, bias, wsI, out);
}

// Round 11
// 65.597 us; speedup vs baseline: 1.1547x; 1.1195x over previous
//
#include <hip/hip_runtime.h>
#include <hip/hip_bf16.h>

// HeteroLinear: out[b,n,o] = sum_i x[b,n,i] * W[t[n]][o][i] + bias[t[n]][o]
// B=16, N=16384, F_IN=F_OUT=128, NUM_TYPES=16, fp32 in/out.
//
// Round 11: R4 geometry (NPB=8, 2064 blocks -> 8.06 blocks/CU, best load
// balance; R10's 528 blocks had a 2.06/CU imbalance tail). Staging made
// near-free: hl_hist pre-converts W to bf16 AND pre-applies the LDS XOR
// swizzle into d_ws (512KB, ws_size-guarded with fallback), so hl_main
// stages via 4x global_load_lds(16B)/wave — no f32 read, no cvt, no
// swizzle math, no VGPR round-trip. Math unchanged (x hi/lo bf16 split).

#define NN 16384
#define FF 128
#define NT 16
#define NPB 8            // nodes per main block (8 waves x 1 node)
#define NBLK (NN / NPB + NT)          // 2064
#define PB 64            // prep blocks
#define WS_PORD 64
#define WS_BH (WS_PORD + NBLK * NPB)  // hist region (ints)
#define WBF_BYTE_OFF 73728            // byte offset of bf16 W images
#define WBF_BYTES (NT * FF * FF * 2)  // 512KB

typedef __bf16 bf16x8 __attribute__((ext_vector_type(8)));
typedef float  f32x4  __attribute__((ext_vector_type(4)));

// ws int layout: [48]=#real blocks; [WS_PORD..) packed node table
// (t<<20 | invalid<<16 | n); [WS_BH..) per-(type,block) hist.
// ws byte layout: [WBF_BYTE_OFF..) pre-swizzled bf16 W[t] LDS images.

__global__ __launch_bounds__(256) void hl_hist(const int* __restrict__ tv,
                                               int* __restrict__ ws,
                                               const float* __restrict__ W,
                                               unsigned char* __restrict__ wbf,
                                               int do_conv) {
    __shared__ int wh[4][NT];
    const int tid = threadIdx.x, lane = tid & 63, wv = tid >> 6;
    const int t = tv[blockIdx.x * 256 + tid];
#pragma unroll
    for (int ty = 0; ty < NT; ++ty) {
        const unsigned long long m = __ballot(t == ty);
        if (lane == 0) wh[wv][ty] = __popcll(m);
    }
    __syncthreads();
    if (tid < NT)
        ws[WS_BH + tid * PB + blockIdx.x] = wh[0][tid] + wh[1][tid] + wh[2][tid] + wh[3][tid];

    if (do_conv) {
        // 32768 chunks of 8 floats; 16384 threads -> 2 chunks each.
#pragma unroll
        for (int c = 0; c < 2; ++c) {
            const int idx = c * 16384 + blockIdx.x * 256 + tid;
            const int ty  = idx >> 11;          // 2048 chunks per type
            const int id  = idx & 2047;
            const int o   = id >> 4;            // W row
            const int kb  = (id & 15) << 4;     // byte col within 256B row
            const float* p = W + ty * (FF * FF) + o * FF + (id & 15) * 8;
            f32x4 a = *(const f32x4*)p;
            f32x4 b = *(const f32x4*)(p + 4);
            bf16x8 v;
#pragma unroll
            for (int j = 0; j < 4; ++j) { v[j] = (__bf16)a[j]; v[4 + j] = (__bf16)b[j]; }
            *(bf16x8*)(wbf + ty * 32768 + o * 256 + (kb ^ ((o & 7) << 4))) = v;
        }
    }
}

__global__ __launch_bounds__(256) void hl_scatter(const int* __restrict__ tv,
                                                  int* __restrict__ ws) {
    __shared__ int bh[NT * PB];
    __shared__ int scnt[NT], mybase[NT], sblk[NT + 1];
    __shared__ int wh[4][NT], wbase[4][NT];
    const int tid = threadIdx.x, lane = tid & 63, wv = tid >> 6;

    for (int i = tid; i < NT * PB; i += 256) bh[i] = ws[WS_BH + i];

    const int n = blockIdx.x * 256 + tid;
    const int t = tv[n];
    int myrank = 0;
#pragma unroll
    for (int ty = 0; ty < NT; ++ty) {
        const unsigned long long m = __ballot(t == ty);
        if (lane == 0) wh[wv][ty] = __popcll(m);
        if (t == ty) myrank = __popcll(m & ((1ull << lane) - 1ull));
    }
    __syncthreads();
    if (tid < NT) {                 // per-type: global count + my block's base
        int acc = 0, myb = 0;
        for (int b = 0; b < PB; ++b) {
            if (b == (int)blockIdx.x) myb = acc;
            acc += bh[tid * PB + b];
        }
        scnt[tid] = acc;
        mybase[tid] = myb;
    }
    __syncthreads();
    if (tid == 0) {                 // padded block offsets per type
        int bacc = 0;
        for (int ty = 0; ty < NT; ++ty) {
            sblk[ty] = bacc;
            bacc += (scnt[ty] + NPB - 1) / NPB;
        }
        sblk[NT] = bacc;
        if (blockIdx.x == 0) ws[48] = bacc;
    }
    __syncthreads();
    if (tid < NT) {
        int base = sblk[tid] * NPB + mybase[tid];
        for (int w = 0; w < 4; ++w) { wbase[w][tid] = base; base += wh[w][tid]; }
    }
    __syncthreads();
    ws[WS_PORD + wbase[wv][t] + myrank] = (t << 20) | n;     // valid entry

    if (blockIdx.x == 0 && tid < NT) {                       // typed sentinels
        const int lo = sblk[tid] * NPB + scnt[tid];
        const int hi = sblk[tid + 1] * NPB;
        for (int s = lo; s < hi; ++s) ws[WS_PORD + s] = (tid << 20) | 0x10000;
    }
}

template <int PRE>
__global__ __launch_bounds__(512, 4) void hl_main(
    const float* __restrict__ x,              // [16][NN][128]
    const float* __restrict__ W,              // [16][128][128]
    const unsigned char* __restrict__ wbf,    // pre-swizzled bf16 W images
    const float* __restrict__ bias,           // [16][128]
    const int*   __restrict__ ws,
    float*       __restrict__ out)            // [16][NN][128]
{
    const int lane = threadIdx.x & 63;
    const int wv   = threadIdx.x >> 6;   // 0..7 = node slot
    const int bid  = blockIdx.x;

    const int e0 = ws[WS_PORD + bid * NPB + wv];
    if (bid >= ws[48]) return;

    const int  t  = e0 >> 20;
    const bool v0 = !(e0 & 0x10000);
    const int  n0 = e0 & 0x3FFF;

    const int lrow = lane & 15;   // A row (b) / B col (o) / D col (o)
    const int lgrp = lane >> 4;   // k-group of 8 / D row-group

    // x loads in flight under W staging
    const float* xbase = x + (size_t)lrow * ((size_t)NN * FF) + lgrp * 8;
    f32x4 xv[8];
#pragma unroll
    for (int kk = 0; kk < 4; ++kk) {
        const float* xp = xbase + (size_t)n0 * FF + kk * 32;
        xv[2 * kk]     = *(const f32x4*)xp;
        xv[2 * kk + 1] = *(const f32x4*)(xp + 4);
    }

    float bv[8];
#pragma unroll
    for (int ot = 0; ot < 8; ++ot) bv[ot] = bias[t * FF + ot * 16 + lrow];

    // stage W[t]: LDS image is pre-built -> pure linear copy
    __shared__ __align__(16) unsigned char Wl[FF * 256];
    if constexpr (PRE) {
#if __has_builtin(__builtin_amdgcn_global_load_lds)
        const unsigned char* wsrc = wbf + t * 32768 + wv * 4096 + lane * 16;
#pragma unroll
        for (int j = 0; j < 4; ++j) {
            __builtin_amdgcn_global_load_lds(
                (const __attribute__((address_space(1))) unsigned int*)(wsrc + j * 1024),
                (__attribute__((address_space(3))) unsigned int*)(Wl + wv * 4096 + j * 1024),
                16, 0, 0);
        }
#else
#pragma unroll
        for (int ii = 0; ii < 4; ++ii) {
            const int idx = ii * 512 + threadIdx.x;
            *(bf16x8*)(Wl + idx * 16) = *(const bf16x8*)(wbf + t * 32768 + idx * 16);
        }
#endif
    } else {
        const float* Wt = W + t * (FF * FF);
#pragma unroll
        for (int ii = 0; ii < 4; ++ii) {
            const int idx = ii * 512 + threadIdx.x;
            const float* p = Wt + idx * 8;
            f32x4 a = *(const f32x4*)p;
            f32x4 b = *(const f32x4*)(p + 4);
            bf16x8 vv;
#pragma unroll
            for (int j = 0; j < 4; ++j) { vv[j] = (__bf16)a[j]; vv[4 + j] = (__bf16)b[j]; }
            const int o  = idx >> 4;
            const int cb = (idx & 15) << 4;
            *(bf16x8*)(Wl + o * 256 + (cb ^ ((o & 7) << 4))) = vv;
        }
    }
    __syncthreads();

    // convert x to hi/lo bf16 (consumes xv)
    bf16x8 ahi[4], alo[4];
#pragma unroll
    for (int kk = 0; kk < 4; ++kk) {
#pragma unroll
        for (int j = 0; j < 4; ++j) {
            const float f0 = xv[2 * kk][j], f1 = xv[2 * kk + 1][j];
            const __bf16 h0 = (__bf16)f0, h1 = (__bf16)f1;
            ahi[kk][j]     = h0;  alo[kk][j]     = (__bf16)(f0 - (float)h0);
            ahi[kk][4 + j] = h1;  alo[kk][4 + j] = (__bf16)(f1 - (float)h1);
        }
    }

    f32x4 acc[8];
#pragma unroll
    for (int ot = 0; ot < 8; ++ot) acc[ot] = (f32x4){0.f, 0.f, 0.f, 0.f};
#pragma unroll
    for (int kk = 0; kk < 4; ++kk) {
#pragma unroll
        for (int ot = 0; ot < 8; ++ot) {
            const int o  = ot * 16 + lrow;
            const int cb = (kk * 64 + lgrp * 16) ^ ((o & 7) << 4);
            const bf16x8 wf = *(const bf16x8*)(Wl + o * 256 + cb);
            acc[ot] = __builtin_amdgcn_mfma_f32_16x16x32_bf16(ahi[kk], wf, acc[ot], 0, 0, 0);
            acc[ot] = __builtin_amdgcn_mfma_f32_16x16x32_bf16(alo[kk], wf, acc[ot], 0, 0, 0);
        }
    }

    if (v0) {
#pragma unroll
        for (int ot = 0; ot < 8; ++ot) {
            const int o = ot * 16 + lrow;
#pragma unroll
            for (int r = 0; r < 4; ++r) {
                out[(size_t)(lgrp * 4 + r) * ((size_t)NN * FF) + (size_t)n0 * FF + o]
                    = acc[ot][r] + bv[ot];
            }
        }
    }
}

extern "C" void kernel_launch(void* const* d_in, const int* in_sizes, int n_in,
                              void* d_out, int out_size, void* d_ws, size_t ws_size,
                              hipStream_t stream) {
    const float* x    = (const float*)d_in[0];
    const int*   tv   = (const int*)d_in[1];
    const float* W    = (const float*)d_in[2];
    const float* bias = (const float*)d_in[3];
    float*       out  = (float*)d_out;
    int*         wsI  = (int*)d_ws;
    unsigned char* wbf = (unsigned char*)d_ws + WBF_BYTE_OFF;

    const int pre = (ws_size >= (size_t)WBF_BYTE_OFF + WBF_BYTES) ? 1 : 0;

    hl_hist<<<PB, 256, 0, stream>>>(tv, wsI, W, wbf, pre);
    hl_scatter<<<PB, 256, 0, stream>>>(tv, wsI);
    if (pre) hl_main<1><<<NBLK, 512, 0, stream>>>(x, W, wbf, bias, wsI, out);
    else     hl_main<0><<<NBLK, 512, 0, stream>>>(x, W, wbf, bias, wsI, out);
}